// Round 11
// baseline (406.614 us; speedup 1.0000x reference)
//
#include <hip/hip_runtime.h>
#include <hip/hip_bf16.h>
#include <cstdint>

typedef __bf16 bf16_t;
typedef __bf16 bf16x4 __attribute__((ext_vector_type(4)));
typedef __bf16 bf16x8 __attribute__((ext_vector_type(8)));
typedef float floatx4 __attribute__((ext_vector_type(4)));
typedef unsigned int u32;
typedef unsigned short ushort8 __attribute__((ext_vector_type(8)));
typedef unsigned int u32x2 __attribute__((ext_vector_type(2)));

#define LNEPS 1e-5f

__device__ inline void async_copy16(const bf16_t* g, bf16_t* l) {
    __builtin_amdgcn_global_load_lds((const __attribute__((address_space(1))) void*)g,
                                     (__attribute__((address_space(3))) void*)l,
                                     16, 0, 0);
}

// ---------------------------------------------------------------------------
// K_prep: fused independent prep work, one dispatch:
//   blocks [0, 18816)          : x[:,1:,:] fp32 -> bf16 xbf  (BW-bound bulk)
//   blocks [18816, 19200)      : transpose proj_w -> Wt bf16 (16 x 24 tiles)
//   blocks [19200, 19456)      : cls fp32->bf16 into Xb + zero pads + csum
//   blocks [19456, 23168)      : build Wb[n][k] bf16 (116 x 32 tiles)
// ---------------------------------------------------------------------------
__global__ __launch_bounds__(256)
void k_prep(const float* __restrict__ x,   bf16_t* __restrict__ xbf,
            const float* __restrict__ w,   bf16_t* __restrict__ wt,
            const float* __restrict__ cls, bf16_t* __restrict__ Xb,
            float* __restrict__ csum,
            const float* __restrict__ W1,  const float* __restrict__ W2,
            bf16_t* __restrict__ Wb)
{
    __shared__ bf16_t tile[32][33];
    const int bid = blockIdx.x;
    const int t = threadIdx.x;

    if (bid < 18816) {                    // ---- cvt_x ----
        const int vid = bid * 256 + t;    // 8-float chunk, 4,816,896 total
        const int row = vid / 96;         // 0..50175
        const int kv  = vid - row * 96;
        const int b = row / 196, l = row - (row / 196) * 196;
        const float* src = x + ((b * 197 + l + 1) * 96 + kv) * 8;
        const floatx4 f0 = *(const floatx4*)src;
        const floatx4 f1 = *(const floatx4*)(src + 4);
        bf16x8 o;
#pragma unroll
        for (int e = 0; e < 4; e++) { o[e] = (bf16_t)f0[e]; o[e+4] = (bf16_t)f1[e]; }
        *(bf16x8*)(xbf + vid * 8) = o;
    } else if (bid < 19200) {             // ---- transpose_w ----
        const int id = bid - 18816;
        const int bx = id & 15;           // n-tile (16)
        const int by = id >> 4;           // k-tile (24)
        const int tx = t & 31, ty = t >> 5;
        for (int i = ty; i < 32; i += 8)
            tile[i][tx] = (bf16_t)w[(by*32 + i)*512 + bx*32 + tx];
        __syncthreads();
        for (int i = ty; i < 32; i += 8)
            wt[(bx*32 + i)*768 + by*32 + tx] = tile[tx][i];
    } else if (bid < 19456) {             // ---- cvt_cls + csum zero ----
        const int b = bid - 19200;
        for (int k = t; k < 768; k += 256)
            Xb[b*3712 + k] = (bf16_t)cls[b*768 + k];
        if (t < 61) Xb[b*3712 + 3651 + t] = (bf16_t)0.f;
        float* cz = csum + b*512;
        cz[t] = 0.f; cz[t + 256] = 0.f;
    } else {                              // ---- cvt_w ----
        const int id = bid - 19456;       // 0..3711
        const int k0 = (id % 116) * 32;
        const int n0 = (id / 116) * 32;
        const int tx = t & 31, ty = t >> 5;
        for (int i = ty; i < 32; i += 8) {
            const int k = k0 + i, n = n0 + tx;
            float v = 0.f;
            if (n < 1000 && k < 3651)
                v = (k < 768) ? W1[k*1000 + n] : W2[(k-768)*1000 + n];
            tile[i][tx] = (bf16_t)v;
        }
        __syncthreads();
        for (int i = ty; i < 32; i += 8)
            Wb[(n0 + i)*3712 + k0 + tx] = tile[tx][i];
    }
}

// ---------------------------------------------------------------------------
// K1: xp = xbf @ Wt^T + b, fused per-head LayerNorm + column sums.
// FAT-WAVE redesign (LDS-BW bound diagnosis): block = 256 rows x 128 cols
// (one head), 4 waves, wave-tile 64x128 (i=4, j=8 -> 2.67 MFMA/KB of LDS
// read vs 1.6 before; per-row LDS traffic 1.55x lower; A staged once per
// 256 rows). Same r8-proven 3-deep counted-vmcnt schedule, 6 gloads/thread
// per step -> vmcnt(12) steady, 6/0 tail. LDS 72 KB -> 2 blocks/CU
// (pipeline depth covers latency, r5). Colsum epilogue: 3 buckets (256-row
// tile straddles <=2 batch boundaries).
// ---------------------------------------------------------------------------
__global__ __launch_bounds__(256, 2)
void k_proj_ln(const bf16_t* __restrict__ xbf, const bf16_t* __restrict__ wt,
               const float* __restrict__ pb, const float* __restrict__ lng,
               const float* __restrict__ lnb, bf16_t* __restrict__ hn,
               float* __restrict__ csum)
{
    __shared__ bf16_t As[3][256*32];      // 48 KB
    __shared__ bf16_t Bs[3][128*32];      // 24 KB

    const int t = threadIdx.x;
    const int lane = t & 63;
    const int wv = t >> 6;                // wave 0..3 -> rows wv*64..wv*64+63
    const int q = lane >> 4;
    const int c = lane & 15;
    const int h  = blockIdx.x & 3;        // head
    const int m0 = (blockIdx.x >> 2) * 256;

    const int srow  = t >> 2;             // 0..63
    const int skoff = (t & 3) * 8;
    const bf16_t* ag0 = xbf + (size_t)(m0 + srow) * 768 + skoff;
    const bf16_t* ag1 = ag0 +  64*768;
    const bf16_t* ag2 = ag0 + 128*768;
    const bf16_t* ag3 = ag0 + 192*768;
    const bf16_t* bg  = wt + (h*128 + srow) * 768 + skoff;
    const bf16_t* bg2 = bg + 64*768;

#define STAGE(B, kk)                                                     \
    {                                                                    \
        const int kn_ = (kk) * 32;                                       \
        async_copy16(ag0 + kn_, &As[B][t*8]);                            \
        async_copy16(ag1 + kn_, &As[B][2048 + t*8]);                     \
        async_copy16(ag2 + kn_, &As[B][4096 + t*8]);                     \
        async_copy16(ag3 + kn_, &As[B][6144 + t*8]);                     \
        async_copy16(bg  + kn_, &Bs[B][t*8]);                            \
        async_copy16(bg2 + kn_, &Bs[B][2048 + t*8]);                     \
    }

#define COMPUTE(B)                                                       \
    {                                                                    \
        bf16x8 af[4], bfr[8];                                            \
        _Pragma("unroll")                                                \
        for (int i = 0; i < 4; i++)                                      \
            af[i] = *(const bf16x8*)&As[B][(wv*64 + i*16 + c)*32 + q*8]; \
        _Pragma("unroll")                                                \
        for (int j = 0; j < 8; j++)                                      \
            bfr[j] = *(const bf16x8*)&Bs[B][(j*16 + c)*32 + q*8];        \
        _Pragma("unroll")                                                \
        for (int i = 0; i < 4; i++)                                      \
            _Pragma("unroll")                                            \
            for (int j = 0; j < 8; j++)                                  \
                acc[i][j] = __builtin_amdgcn_mfma_f32_16x16x32_bf16(af[i], bfr[j], acc[i][j], 0, 0, 0); \
    }

    floatx4 acc[4][8];
#pragma unroll
    for (int i = 0; i < 4; i++)
#pragma unroll
        for (int j = 0; j < 8; j++)
#pragma unroll
            for (int r = 0; r < 4; r++) acc[i][j][r] = 0.f;

    // prologue: stage tiles 0,1,2 (18 gloads/thread in flight)
    STAGE(0, 0);
    STAGE(1, 1);
    STAGE(2, 2);

    for (int ks = 0; ks < 22; ks++) {
        const int buf = ks % 3;
        // tile ks complete (own 6 oldest); tiles ks+1,ks+2 (12) in flight
        asm volatile("s_waitcnt vmcnt(12)" ::: "memory");
        __builtin_amdgcn_s_barrier();
        COMPUTE(buf);
        __builtin_amdgcn_s_barrier();
        if (ks < 21) STAGE(buf, ks + 3);
    }
    // peeled tail: ks=22 (outstanding 12 -> wait to 6), ks=23 (drain)
    asm volatile("s_waitcnt vmcnt(6)" ::: "memory");
    __builtin_amdgcn_s_barrier();
    COMPUTE(1);
    __builtin_amdgcn_s_barrier();
    asm volatile("s_waitcnt vmcnt(0)" ::: "memory");
    __builtin_amdgcn_s_barrier();
    COMPUTE(2);

#undef STAGE
#undef COMPUTE

    // epilogue: +bias, LN over this wave's head (128 cols = 8j x 16c),
    // plus per-column partial sums over up to 3 straddled batches
    float bias[8], gg[8], bb[8];
#pragma unroll
    for (int j = 0; j < 8; j++) {
        const int d = j*16 + c;
        bias[j] = pb[h*128 + d];
        gg[j]   = lng[d];
        bb[j]   = lnb[d];
    }
    float cs0[8], cs1[8], cs2[8];
#pragma unroll
    for (int j = 0; j < 8; j++) { cs0[j] = 0.f; cs1[j] = 0.f; cs2[j] = 0.f; }
    const int b0 = m0 / 196;
    const int bL = (m0 + 255) / 196;
#pragma unroll
    for (int i = 0; i < 4; i++) {
#pragma unroll
        for (int r = 0; r < 4; r++) {
            float s = 0.f, s2 = 0.f;
#pragma unroll
            for (int j = 0; j < 8; j++) {
                const float v = acc[i][j][r] + bias[j];
                acc[i][j][r] = v;
                s += v; s2 += v*v;
            }
#pragma unroll
            for (int o = 1; o < 16; o <<= 1) { s += __shfl_xor(s, o); s2 += __shfl_xor(s2, o); }
            const float mu = s * (1.f/128.f);
            const float ms = s2 * (1.f/128.f);
            const float rstd = rsqrtf(ms - mu*mu + LNEPS);
            const int gm = m0 + wv*64 + i*16 + q*4 + r;
            const int bI = gm / 196, l = gm - bI*196;
            bf16_t* dst = hn + (((h*256 + bI)*196 + l) << 7);
            const int bk = bI - b0;
#pragma unroll
            for (int j = 0; j < 8; j++) {
                const float v = (acc[i][j][r] - mu)*rstd*gg[j] + bb[j];
                dst[j*16 + c] = (bf16_t)v;
                cs0[j] += (bk == 0) ? v : 0.f;
                cs1[j] += (bk == 1) ? v : 0.f;
                cs2[j] += (bk == 2) ? v : 0.f;
            }
        }
    }
    // column-sum reduce: over q (shfl), over waves (LDS scratch in As[0],
    // 6 KB; last COMPUTE read As[2]/Bs[2] -> no overlap), atomicAdd
    float* scr = (float*)As;              // [wv*3 + bucket][128]
#pragma unroll
    for (int j = 0; j < 8; j++) {
        float s0 = cs0[j], s1 = cs1[j], s2 = cs2[j];
        s0 += __shfl_xor(s0, 16); s0 += __shfl_xor(s0, 32);
        s1 += __shfl_xor(s1, 16); s1 += __shfl_xor(s1, 32);
        s2 += __shfl_xor(s2, 16); s2 += __shfl_xor(s2, 32);
        if (q == 0) {
            scr[(wv*3 + 0)*128 + j*16 + c] = s0;
            scr[(wv*3 + 1)*128 + j*16 + c] = s1;
            scr[(wv*3 + 2)*128 + j*16 + c] = s2;
        }
    }
    __syncthreads();
    if (t < 128) {
        const int d = t;
#pragma unroll
        for (int bucket = 0; bucket < 3; bucket++) {
            if (bucket <= bL - b0) {
                const float s = scr[(0*3 + bucket)*128 + d] + scr[(1*3 + bucket)*128 + d]
                              + scr[(2*3 + bucket)*128 + d] + scr[(3*3 + bucket)*128 + d];
                atomicAdd(&csum[((h*256 + b0 + bucket) << 7) + d], s);
            }
        }
    }
}

// ---------------------------------------------------------------------------
// K2: per (p,b): raw = x1^T @ x2 (K=196 padded to 224), centering correction,
//     column L2 normalize over d, write cov[b][p][d][e] fp32.
// Packed-u32 transpose staging (2-way write banks, free) + T14 async split.
// ---------------------------------------------------------------------------
__global__ __launch_bounds__(256, 3)
void k_cov(const bf16_t* __restrict__ hn, const float* __restrict__ colsum,
           float* __restrict__ cov)
{
    __shared__ u32 x1s[128*18];           // 9216 B
    __shared__ u32 x2s[128*18];
    __shared__ float rs1[128], rs2[128];
    __shared__ float colsq[2][128];
    __shared__ float nrm_inv[128];
    __shared__ float mu_s[2];

    const int t = threadIdx.x;
    const int lane = t & 63;
    const int wv = t >> 6;
    const int wr = wv >> 1, wc = wv & 1;
    const int q = lane >> 4;
    const int c = lane & 15;
    const int b = blockIdx.x;
    const int p = blockIdx.y;

    const bf16_t* X1 = hn + (((p*256 + b)*196) << 7);
    const bf16_t* X2 = hn + ((((p+1)*256 + b)*196) << 7);

    if (t < 128) rs1[t] = colsum[((p*256 + b) << 7) + t];
    else         rs2[t & 127] = colsum[(((p+1)*256 + b) << 7) + (t & 127)];
    __syncthreads();
    if (wv == 0) {
        float s = rs1[lane] + rs1[lane + 64];
#pragma unroll
        for (int o = 1; o < 64; o <<= 1) s += __shfl_xor(s, o);
        if (lane == 0) mu_s[0] = s * (1.f/(196.f*128.f));
    } else if (wv == 1) {
        float s = rs2[lane] + rs2[lane + 64];
#pragma unroll
        for (int o = 1; o < 64; o <<= 1) s += __shfl_xor(s, o);
        if (lane == 0) mu_s[1] = s * (1.f/(196.f*128.f));
    }

    floatx4 acc[4][4];
#pragma unroll
    for (int i = 0; i < 4; i++)
#pragma unroll
        for (int j = 0; j < 4; j++)
#pragma unroll
            for (int r = 0; r < 4; r++) acc[i][j][r] = 0.f;

    const int np  = t & 15;               // token pair 0..15
    const int dch = t >> 4;               // d-chunk of 8, 0..15

    ushort8 cva, cvb, cwa, cwb;           // current tile regs
    {                                     // prologue: tile n0=0 (all n<196)
        const int na = 2*np, nb = na + 1;
        cva = *(const ushort8*)(X1 + (na << 7) + dch*8);
        cwa = *(const ushort8*)(X2 + (na << 7) + dch*8);
        cvb = *(const ushort8*)(X1 + (nb << 7) + dch*8);
        cwb = *(const ushort8*)(X2 + (nb << 7) + dch*8);
    }

    for (int n0 = 0; n0 < 224; n0 += 32) {
        __syncthreads();                  // prev iteration's LDS reads done
#pragma unroll
        for (int e = 0; e < 8; e++) {     // pack/write current tile
            x1s[(dch*8 + e)*18 + np] = (u32)cva[e] | ((u32)cvb[e] << 16);
            x2s[(dch*8 + e)*18 + np] = (u32)cwa[e] | ((u32)cwb[e] << 16);
        }
        __syncthreads();                  // writes visible
        if (n0 + 32 < 224) {              // T14: issue next tile's loads NOW
            const int na = n0 + 32 + 2*np, nb = na + 1;
            ushort8 z;
#pragma unroll
            for (int e = 0; e < 8; e++) z[e] = 0;
            ushort8 nva = z, nvb = z, nwa = z, nwb = z;
            if (na < 196) {
                nva = *(const ushort8*)(X1 + (na << 7) + dch*8);
                nwa = *(const ushort8*)(X2 + (na << 7) + dch*8);
            }
            if (nb < 196) {
                nvb = *(const ushort8*)(X1 + (nb << 7) + dch*8);
                nwb = *(const ushort8*)(X2 + (nb << 7) + dch*8);
            }
            cva = nva; cvb = nvb; cwa = nwa; cwb = nwb;
        }
        bf16x8 af[4], bfr[4];             // MFMA cluster hides the loads
#pragma unroll
        for (int i = 0; i < 4; i++) {
            const int base = (wr*64 + i*16 + c)*18 + q*4;
            u32 tmp[4];
            *(u32x2*)&tmp[0] = *(const u32x2*)&x1s[base];
            *(u32x2*)&tmp[2] = *(const u32x2*)&x1s[base + 2];
            __builtin_memcpy(&af[i], tmp, 16);
        }
#pragma unroll
        for (int j = 0; j < 4; j++) {
            const int base = (wc*64 + j*16 + c)*18 + q*4;
            u32 tmp[4];
            *(u32x2*)&tmp[0] = *(const u32x2*)&x2s[base];
            *(u32x2*)&tmp[2] = *(const u32x2*)&x2s[base + 2];
            __builtin_memcpy(&bfr[j], tmp, 16);
        }
#pragma unroll
        for (int i = 0; i < 4; i++)
#pragma unroll
            for (int j = 0; j < 4; j++)
                acc[i][j] = __builtin_amdgcn_mfma_f32_16x16x32_bf16(af[i], bfr[j], acc[i][j], 0, 0, 0);
    }

    const float mu1 = mu_s[0], mu2 = mu_s[1];
    const float invL = 1.f/196.f;
    float csq[4] = {0.f, 0.f, 0.f, 0.f};
#pragma unroll
    for (int i = 0; i < 4; i++)
#pragma unroll
        for (int j = 0; j < 4; j++)
#pragma unroll
            for (int r = 0; r < 4; r++) {
                const int d = wr*64 + i*16 + q*4 + r;
                const int e = wc*64 + j*16 + c;
                const float v = acc[i][j][r]*invL - mu2*rs1[d]*invL - mu1*rs2[e]*invL + mu1*mu2;
                acc[i][j][r] = v;
                csq[j] += v*v;
            }
#pragma unroll
    for (int j = 0; j < 4; j++) {
        float s = csq[j];
        s += __shfl_xor(s, 16);
        s += __shfl_xor(s, 32);
        csq[j] = s;
    }
    if (q == 0) {
#pragma unroll
        for (int j = 0; j < 4; j++) colsq[wr][wc*64 + j*16 + c] = csq[j];
    }
    __syncthreads();
    if (t < 128) {
        const float nr = sqrtf(colsq[0][t] + colsq[1][t]);
        nrm_inv[t] = 1.f / fmaxf(nr, 1e-12f);
    }
    __syncthreads();
    float* dst = cov + ((long)b*3 + p)*16384;
#pragma unroll
    for (int i = 0; i < 4; i++)
#pragma unroll
        for (int j = 0; j < 4; j++) {
            const int e = wc*64 + j*16 + c;
            const float ni = nrm_inv[e];
#pragma unroll
            for (int r = 0; r < 4; r++) {
                const int d = wr*64 + i*16 + q*4 + r;
                dst[(d << 7) + e] = acc[i][j][r] * ni;
            }
        }
}

// ---------------------------------------------------------------------------
// K3: fused conv1+GELU+conv2; 2 blocks per batch (conv2 y-halves) -> 512
// blocks = 2 blocks/CU. Z slice (<=33 rows, 1-row overlap) kept in LDS.
// ---------------------------------------------------------------------------
__global__ __launch_bounds__(256)
void k_convs(const float* __restrict__ cov, const float* __restrict__ w1,
             const float* __restrict__ w2, bf16_t* __restrict__ Xb)
{
    __shared__ float Z[3*33*63];          // 24.9 KB
    __shared__ float W1s[81];
    __shared__ float W2s[81];
    const int t = threadIdx.x;
    const int b = blockIdx.x >> 1, half = blockIdx.x & 1;
    const int zy0 = half ? 32 : 0;        // first global Z row this block needs
    const int nzy = half ? 31 : 33;       // Z rows computed
    const int y20 = half ? 16 : 0;        // first conv2 output row
    const int ny2 = half ? 15 : 16;       // conv2 output rows
    if (t < 81) { W1s[t] = w1[t]; W2s[t] = w2[t]; }
    __syncthreads();
    const float* C = cov + (long)b*3*16384;
    const int ztot = 3*nzy*63;
    for (int idx = t; idx < ztot; idx += 256) {
        const int o = idx / (nzy*63), rem = idx - o*(nzy*63);
        const int yl = rem / 63, xx = rem - yl*63;
        const int y = zy0 + yl;
        float a = 0.f;
#pragma unroll
        for (int i = 0; i < 3; i++) {
            const float* Ci = C + i*16384 + (2*y)*128 + 2*xx;
            const float* Wi = &W1s[o*27 + i*9];
            a += Ci[0]*Wi[0]   + Ci[1]*Wi[1]   + Ci[2]*Wi[2]
               + Ci[128]*Wi[3] + Ci[129]*Wi[4] + Ci[130]*Wi[5]
               + Ci[256]*Wi[6] + Ci[257]*Wi[7] + Ci[258]*Wi[8];
        }
        Z[o*2079 + yl*63 + xx] = 0.5f*a*(1.0f + erff(a*0.70710678118654752f));
    }
    __syncthreads();
    const int c2tot = 3*ny2*31;
    for (int idx = t; idx < c2tot; idx += 256) {
        const int o = idx / (ny2*31), rem = idx - o*(ny2*31);
        const int y2l = rem / 31, x2 = rem - y2l*31;
        float a = 0.f;
#pragma unroll
        for (int i = 0; i < 3; i++) {
            const float* Zi = Z + i*2079 + (2*y2l)*63 + 2*x2;
            const float* Wi = &W2s[(o*3+i)*9];
            a += Zi[0]*Wi[0]   + Zi[1]*Wi[1]   + Zi[2]*Wi[2]
               + Zi[63]*Wi[3]  + Zi[64]*Wi[4]  + Zi[65]*Wi[5]
               + Zi[126]*Wi[6] + Zi[127]*Wi[7] + Zi[128]*Wi[8];
        }
        const int oy2 = y20 + y2l;
        Xb[(long)b*3712 + 768 + o*961 + oy2*31 + x2] = (bf16_t)a;
    }
}

// ---------------------------------------------------------------------------
// K4c: MFMA GEMM partial[s][m][n] = Xb[m][ks..] @ Wb[n][ks..]^T
// grid (nt=8, mt=2, split=4); 128x128 tile, K-split 928 (29 k-tiles) each.
// Triple-buffered counted-vmcnt pipeline (r8).
// ---------------------------------------------------------------------------
__global__ __launch_bounds__(256, 2)
void k_gemm_cls(const bf16_t* __restrict__ Xb, const bf16_t* __restrict__ Wb,
                float* __restrict__ partial)
{
    __shared__ bf16_t As[3][128*32];
    __shared__ bf16_t Bs[3][128*32];

    const int t = threadIdx.x;
    const int lane = t & 63;
    const int wv = t >> 6;
    const int wr = wv >> 1, wc = wv & 1;
    const int q = lane >> 4;
    const int c = lane & 15;
    const int nt = blockIdx.x;
    const int mt = blockIdx.y;
    const int sp = blockIdx.z;

    const int srow  = t >> 2;
    const int skoff = (t & 3) * 8;
    const int m0 = mt * 128, n0 = nt * 128;
    const int kbase = sp * 928;
    const bf16_t* ag0 = Xb + (m0 + srow) * 3712 + kbase + skoff;
    const bf16_t* ag1 = Xb + (m0 + srow + 64) * 3712 + kbase + skoff;
    const bf16_t* bg0 = Wb + (n0 + srow) * 3712 + kbase + skoff;
    const bf16_t* bg1 = Wb + (n0 + srow + 64) * 3712 + kbase + skoff;

#define GSTAGE(B, kk)                                                    \
    {                                                                    \
        const int kn_ = (kk) * 32;                                       \
        async_copy16(ag0 + kn_, &As[B][t*8]);                            \
        async_copy16(ag1 + kn_, &As[B][2048 + t*8]);                     \
        async_copy16(bg0 + kn_, &Bs[B][t*8]);                            \
        async_copy16(bg1 + kn_, &Bs[B][2048 + t*8]);                     \
    }

#define GCOMPUTE(B)                                                      \
    {                                                                    \
        bf16x8 af[4], bfr[4];                                            \
        _Pragma("unroll")                                                \
        for (int i = 0; i < 4; i++)                                      \
            af[i] = *(const bf16x8*)&As[B][(wr*64 + i*16 + c)*32 + q*8]; \
        _Pragma("unroll")                                                \
        for (int j = 0; j < 4; j++)                                      \
            bfr[j] = *(const bf16x8*)&Bs[B][(wc*64 + j*16 + c)*32 + q*8];\
        _Pragma("unroll")                                                \
        for (int i = 0; i < 4; i++)                                      \
            _Pragma("unroll")                                            \
            for (int j = 0; j < 4; j++)                                  \
                acc[i][j] = __builtin_amdgcn_mfma_f32_16x16x32_bf16(af[i], bfr[j], acc[i][j], 0, 0, 0); \
    }

    floatx4 acc[4][4];
#pragma unroll
    for (int i = 0; i < 4; i++)
#pragma unroll
        for (int j = 0; j < 4; j++)
#pragma unroll
            for (int r = 0; r < 4; r++) acc[i][j][r] = 0.f;

    GSTAGE(0, 0);
    GSTAGE(1, 1);
    GSTAGE(2, 2);

    for (int ks = 0; ks < 27; ks++) {     // 29 tiles: loop does 0..26
        const int buf = ks % 3;
        asm volatile("s_waitcnt vmcnt(8)" ::: "memory");
        __builtin_amdgcn_s_barrier();
        GCOMPUTE(buf);
        __builtin_amdgcn_s_barrier();
        if (ks < 26) GSTAGE(buf, ks + 3);
    }
    asm volatile("s_waitcnt vmcnt(4)" ::: "memory");
    __builtin_amdgcn_s_barrier();
    GCOMPUTE(0);
    __builtin_amdgcn_s_barrier();
    asm volatile("s_waitcnt vmcnt(0)" ::: "memory");
    __builtin_amdgcn_s_barrier();
    GCOMPUTE(1);

#undef GSTAGE
#undef GCOMPUTE

    float* base = partial + ((long)sp*256 + m0)*1024 + n0;
#pragma unroll
    for (int i = 0; i < 4; i++)
#pragma unroll
        for (int r = 0; r < 4; r++) {
            const int row = wr*64 + i*16 + q*4 + r;
#pragma unroll
            for (int j = 0; j < 4; j++)
                base[row*1024 + wc*64 + j*16 + c] = acc[i][j][r];
        }
}

// ---------------------------------------------------------------------------
// K4d: out[m][n] = 0.5*(sum_s partial[s][m][n] + b1[n] + b2[n]), n<1000
// ---------------------------------------------------------------------------
__global__ __launch_bounds__(256)
void k_cls_fin(const float* __restrict__ partial, const float* __restrict__ b1,
               const float* __restrict__ b2, float* __restrict__ out)
{
    const int idx = blockIdx.x * 256 + threadIdx.x;   // 256,000
    const int m = idx / 1000, n = idx - m*1000;
    float s = partial[(m)*1024 + n] + partial[(256 + m)*1024 + n]
            + partial[(512 + m)*1024 + n] + partial[(768 + m)*1024 + n];
    out[idx] = 0.5f*(s + b1[n] + b2[n]);
}

// ---------------------------------------------------------------------------
extern "C" void kernel_launch(void* const* d_in, const int* in_sizes, int n_in,
                              void* d_out, int out_size, void* d_ws, size_t ws_size,
                              hipStream_t stream) {
    const float* cls = (const float*)d_in[0];
    const float* x   = (const float*)d_in[1];
    const float* pw  = (const float*)d_in[2];
    const float* pb  = (const float*)d_in[3];
    const float* lng = (const float*)d_in[4];
    const float* lnb = (const float*)d_in[5];
    const float* c1w = (const float*)d_in[6];
    const float* c2w = (const float*)d_in[7];
    const float* w1  = (const float*)d_in[8];
    const float* b1  = (const float*)d_in[9];
    const float* w2  = (const float*)d_in[10];
    const float* b2  = (const float*)d_in[11];

    char* ws = (char*)d_ws;
    // lifetimes:
    //   hn      [0, 51,380,224)                 proj_ln out -> cov in
    //   xbf     [51,380,224, +77,070,336)       dead after proj_ln
    //   covb    [51,380,224, +50,331,648)       reuses xbf; cov out -> convs in
    //   wt      [128,450,560, +786,432)         dead after proj_ln
    //   csum    [129,236,992, +524,288)
    //   Xb      [129,761,280, +1,900,544)
    //   Wb      [131,661,824, +7,602,176)
    //   part    [139,264,000, +4,194,304)
    bf16_t* hn    = (bf16_t*)(ws);
    bf16_t* xbf   = (bf16_t*)(ws + 51380224ull);
    float*  covb  = (float*) (ws + 51380224ull);
    bf16_t* wt    = (bf16_t*)(ws + 128450560ull);
    float*  csum  = (float*) (ws + 129236992ull);
    bf16_t* Xb    = (bf16_t*)(ws + 129761280ull);
    bf16_t* Wb    = (bf16_t*)(ws + 131661824ull);
    float*  part  = (float*) (ws + 139264000ull);
    float*  out   = (float*)d_out;

    k_prep<<<23168, 256, 0, stream>>>(x, xbf, pw, wt, cls, Xb, csum, w1, w2, Wb);
    k_proj_ln<<<784, 256, 0, stream>>>(xbf, wt, pb, lng, lnb, hn, csum);
    k_cov<<<dim3(256, 3), 256, 0, stream>>>(hn, csum, covb);
    k_convs<<<512, 256, 0, stream>>>(covb, c1w, c2w, Xb);
    k_gemm_cls<<<dim3(8, 2, 4), 256, 0, stream>>>(Xb, Wb, part);
    k_cls_fin<<<1000, 256, 0, stream>>>(part, b1, b2, out);
}

// Round 12
// 399.551 us; speedup vs baseline: 1.0177x; 1.0177x over previous
//
#include <hip/hip_runtime.h>
#include <hip/hip_bf16.h>
#include <cstdint>

typedef __bf16 bf16_t;
typedef __bf16 bf16x4 __attribute__((ext_vector_type(4)));
typedef __bf16 bf16x8 __attribute__((ext_vector_type(8)));
typedef float floatx4 __attribute__((ext_vector_type(4)));
typedef unsigned int u32;
typedef unsigned short ushort8 __attribute__((ext_vector_type(8)));
typedef unsigned int u32x2 __attribute__((ext_vector_type(2)));

#define LNEPS 1e-5f

__device__ inline void async_copy16(const bf16_t* g, bf16_t* l) {
    __builtin_amdgcn_global_load_lds((const __attribute__((address_space(1))) void*)g,
                                     (__attribute__((address_space(3))) void*)l,
                                     16, 0, 0);
}

// ---------------------------------------------------------------------------
// K_prep: fused independent prep work, one dispatch:
//   blocks [0, 18816)          : x[:,1:,:] fp32 -> bf16 xbf  (BW-bound bulk)
//   blocks [18816, 19200)      : transpose proj_w -> Wt bf16 (16 x 24 tiles)
//   blocks [19200, 19456)      : cls fp32->bf16 into Xb + zero pads + csum
//   blocks [19456, 23168)      : build Wb[n][k] bf16 (116 x 32 tiles)
// ---------------------------------------------------------------------------
__global__ __launch_bounds__(256)
void k_prep(const float* __restrict__ x,   bf16_t* __restrict__ xbf,
            const float* __restrict__ w,   bf16_t* __restrict__ wt,
            const float* __restrict__ cls, bf16_t* __restrict__ Xb,
            float* __restrict__ csum,
            const float* __restrict__ W1,  const float* __restrict__ W2,
            bf16_t* __restrict__ Wb)
{
    __shared__ bf16_t tile[32][33];
    const int bid = blockIdx.x;
    const int t = threadIdx.x;

    if (bid < 18816) {                    // ---- cvt_x ----
        const int vid = bid * 256 + t;    // 8-float chunk, 4,816,896 total
        const int row = vid / 96;         // 0..50175
        const int kv  = vid - row * 96;
        const int b = row / 196, l = row - (row / 196) * 196;
        const float* src = x + ((b * 197 + l + 1) * 96 + kv) * 8;
        const floatx4 f0 = *(const floatx4*)src;
        const floatx4 f1 = *(const floatx4*)(src + 4);
        bf16x8 o;
#pragma unroll
        for (int e = 0; e < 4; e++) { o[e] = (bf16_t)f0[e]; o[e+4] = (bf16_t)f1[e]; }
        *(bf16x8*)(xbf + vid * 8) = o;
    } else if (bid < 19200) {             // ---- transpose_w ----
        const int id = bid - 18816;
        const int bx = id & 15;           // n-tile (16)
        const int by = id >> 4;           // k-tile (24)
        const int tx = t & 31, ty = t >> 5;
        for (int i = ty; i < 32; i += 8)
            tile[i][tx] = (bf16_t)w[(by*32 + i)*512 + bx*32 + tx];
        __syncthreads();
        for (int i = ty; i < 32; i += 8)
            wt[(bx*32 + i)*768 + by*32 + tx] = tile[tx][i];
    } else if (bid < 19456) {             // ---- cvt_cls + csum zero ----
        const int b = bid - 19200;
        for (int k = t; k < 768; k += 256)
            Xb[b*3712 + k] = (bf16_t)cls[b*768 + k];
        if (t < 61) Xb[b*3712 + 3651 + t] = (bf16_t)0.f;
        float* cz = csum + b*512;
        cz[t] = 0.f; cz[t + 256] = 0.f;
    } else {                              // ---- cvt_w ----
        const int id = bid - 19456;       // 0..3711
        const int k0 = (id % 116) * 32;
        const int n0 = (id / 116) * 32;
        const int tx = t & 31, ty = t >> 5;
        for (int i = ty; i < 32; i += 8) {
            const int k = k0 + i, n = n0 + tx;
            float v = 0.f;
            if (n < 1000 && k < 3651)
                v = (k < 768) ? W1[k*1000 + n] : W2[(k-768)*1000 + n];
            tile[i][tx] = (bf16_t)v;
        }
        __syncthreads();
        for (int i = ty; i < 32; i += 8)
            Wb[(n0 + i)*3712 + k0 + tx] = tile[tx][i];
    }
}

// ---------------------------------------------------------------------------
// K1: xp = xbf @ Wt^T + b, fused per-head LayerNorm + column sums.
// r8/r10-proven best: 128x128 tile (1 head/block), pure global_load_lds
// staging, TRIPLE-buffered LDS, counted-vmcnt raw barriers (vmcnt(8) steady
// state), XCD-bijective swizzle, shuffle-only LN + fused column sums.
// [Plateau note: 4 structurally different variants (A-in-reg, fp32-direct,
// fat-wave, this) all measure 84-88 us -> barrier-synced step floor, not
// staging/LDS/occupancy bound. This is the best measured.]
// ---------------------------------------------------------------------------
__global__ __launch_bounds__(256, 3)
void k_proj_ln(const bf16_t* __restrict__ xbf, const bf16_t* __restrict__ wt,
               const float* __restrict__ pb, const float* __restrict__ lng,
               const float* __restrict__ lnb, bf16_t* __restrict__ hn,
               float* __restrict__ csum)
{
    __shared__ bf16_t As[3][128*32];      // 24 KB
    __shared__ bf16_t Bs[3][128*32];      // 24 KB

    const int t = threadIdx.x;
    const int lane = t & 63;
    const int wv = t >> 6;                // wave 0..3 -> rows wv*32..wv*32+31
    const int q = lane >> 4;
    const int c = lane & 15;
    // XCD-bijective: L = xcd + 8*(h + 4*j); m = xcd + 8*j  (392 = 8*49)
    const int L = blockIdx.x;
    const int xcd = L & 7, slot = L >> 3;
    const int h = slot & 3;
    const int m0 = (xcd + 8 * (slot >> 2)) * 128;

    const int srow  = t >> 2;
    const int skoff = (t & 3) * 8;
    const bf16_t* ag = xbf + (m0 + srow) * 768 + skoff;
    const bf16_t* bg = wt + (h*128 + srow) * 768 + skoff;

#define STAGE(B, kk)                                                     \
    {                                                                    \
        const int kn_ = (kk) * 32;                                       \
        async_copy16(ag + kn_,          &As[B][t*8]);                    \
        async_copy16(ag + 64*768 + kn_, &As[B][2048 + t*8]);             \
        async_copy16(bg + kn_,          &Bs[B][t*8]);                    \
        async_copy16(bg + 64*768 + kn_, &Bs[B][2048 + t*8]);             \
    }

#define COMPUTE(B)                                                       \
    {                                                                    \
        bf16x8 af[2], bfr[8];                                            \
        _Pragma("unroll")                                                \
        for (int i = 0; i < 2; i++)                                      \
            af[i] = *(const bf16x8*)&As[B][(wv*32 + i*16 + c)*32 + q*8]; \
        _Pragma("unroll")                                                \
        for (int j = 0; j < 8; j++)                                      \
            bfr[j] = *(const bf16x8*)&Bs[B][(j*16 + c)*32 + q*8];        \
        _Pragma("unroll")                                                \
        for (int i = 0; i < 2; i++)                                      \
            _Pragma("unroll")                                            \
            for (int j = 0; j < 8; j++)                                  \
                acc[i][j] = __builtin_amdgcn_mfma_f32_16x16x32_bf16(af[i], bfr[j], acc[i][j], 0, 0, 0); \
    }

    floatx4 acc[2][8];
#pragma unroll
    for (int i = 0; i < 2; i++)
#pragma unroll
        for (int j = 0; j < 8; j++)
#pragma unroll
            for (int r = 0; r < 4; r++) acc[i][j][r] = 0.f;

    // prologue: stage tiles 0,1,2 (12 gloads/thread in flight)
    STAGE(0, 0);
    STAGE(1, 1);
    STAGE(2, 2);

    for (int ks = 0; ks < 22; ks++) {
        const int buf = ks % 3;
        // tile ks complete (own 4 oldest); tiles ks+1,ks+2 (8) stay in flight
        asm volatile("s_waitcnt vmcnt(8)" ::: "memory");
        __builtin_amdgcn_s_barrier();     // all waves' quarter-tiles published
        COMPUTE(buf);
        __builtin_amdgcn_s_barrier();     // all waves done reading buf
        if (ks < 21) STAGE(buf, ks + 3);
    }
    // peeled tail: ks=22 (outstanding 8 -> wait to 4), ks=23 (drain)
    asm volatile("s_waitcnt vmcnt(4)" ::: "memory");
    __builtin_amdgcn_s_barrier();
    COMPUTE(1);
    __builtin_amdgcn_s_barrier();
    asm volatile("s_waitcnt vmcnt(0)" ::: "memory");
    __builtin_amdgcn_s_barrier();
    COMPUTE(2);

#undef STAGE
#undef COMPUTE

    // epilogue: +bias, LN over this wave's head (128 cols = 8j x 16c),
    // plus per-column partial sums split at the (<=1) batch boundary
    float bias[8], gg[8], bb[8];
#pragma unroll
    for (int j = 0; j < 8; j++) {
        const int d = j*16 + c;
        bias[j] = pb[h*128 + d];
        gg[j]   = lng[d];
        bb[j]   = lnb[d];
    }
    float cs0[8], cs1[8];
#pragma unroll
    for (int j = 0; j < 8; j++) { cs0[j] = 0.f; cs1[j] = 0.f; }
    const int b0 = m0 / 196;
    const int bL = (m0 + 127) / 196;
#pragma unroll
    for (int i = 0; i < 2; i++) {
#pragma unroll
        for (int r = 0; r < 4; r++) {
            float s = 0.f, s2 = 0.f;
#pragma unroll
            for (int j = 0; j < 8; j++) {
                const float v = acc[i][j][r] + bias[j];
                acc[i][j][r] = v;
                s += v; s2 += v*v;
            }
#pragma unroll
            for (int o = 1; o < 16; o <<= 1) { s += __shfl_xor(s, o); s2 += __shfl_xor(s2, o); }
            const float mu = s * (1.f/128.f);
            const float ms = s2 * (1.f/128.f);
            const float rstd = rsqrtf(ms - mu*mu + LNEPS);
            const int gm = m0 + wv*32 + i*16 + q*4 + r;
            const int bI = gm / 196, l = gm - bI*196;
            bf16_t* dst = hn + (((h*256 + bI)*196 + l) << 7);
            const bool first = (bI == b0);
#pragma unroll
            for (int j = 0; j < 8; j++) {
                const float v = (acc[i][j][r] - mu)*rstd*gg[j] + bb[j];
                dst[j*16 + c] = (bf16_t)v;
                cs0[j] += first ? v : 0.f;
                cs1[j] += first ? 0.f : v;
            }
        }
    }
    // column-sum reduce: over q (shfl), over waves (LDS scratch), atomicAdd
    float* scr = (float*)As;
#pragma unroll
    for (int j = 0; j < 8; j++) {
        float s0 = cs0[j], s1 = cs1[j];
        s0 += __shfl_xor(s0, 16); s0 += __shfl_xor(s0, 32);
        s1 += __shfl_xor(s1, 16); s1 += __shfl_xor(s1, 32);
        if (q == 0) {
            scr[(wv*2 + 0)*128 + j*16 + c] = s0;
            scr[(wv*2 + 1)*128 + j*16 + c] = s1;
        }
    }
    __syncthreads();
    {
        const int bucket = t >> 7, d = t & 127;
        if (bucket == 0 || bL > b0) {
            const float s = scr[(0*2 + bucket)*128 + d] + scr[(1*2 + bucket)*128 + d]
                          + scr[(2*2 + bucket)*128 + d] + scr[(3*2 + bucket)*128 + d];
            atomicAdd(&csum[((h*256 + b0 + bucket) << 7) + d], s);
        }
    }
}

// ---------------------------------------------------------------------------
// K2: per (p,b): raw = x1^T @ x2 (K=196 padded to 224), centering correction,
//     column L2 normalize over d, write cov[b][p][d][e] fp32.
// Packed-u32 transpose staging (2-way write banks, free) + T14 async split.
// ---------------------------------------------------------------------------
__global__ __launch_bounds__(256, 3)
void k_cov(const bf16_t* __restrict__ hn, const float* __restrict__ colsum,
           float* __restrict__ cov)
{
    __shared__ u32 x1s[128*18];           // 9216 B
    __shared__ u32 x2s[128*18];
    __shared__ float rs1[128], rs2[128];
    __shared__ float colsq[2][128];
    __shared__ float nrm_inv[128];
    __shared__ float mu_s[2];

    const int t = threadIdx.x;
    const int lane = t & 63;
    const int wv = t >> 6;
    const int wr = wv >> 1, wc = wv & 1;
    const int q = lane >> 4;
    const int c = lane & 15;
    const int b = blockIdx.x;
    const int p = blockIdx.y;

    const bf16_t* X1 = hn + (((p*256 + b)*196) << 7);
    const bf16_t* X2 = hn + ((((p+1)*256 + b)*196) << 7);

    if (t < 128) rs1[t] = colsum[((p*256 + b) << 7) + t];
    else         rs2[t & 127] = colsum[(((p+1)*256 + b) << 7) + (t & 127)];
    __syncthreads();
    if (wv == 0) {
        float s = rs1[lane] + rs1[lane + 64];
#pragma unroll
        for (int o = 1; o < 64; o <<= 1) s += __shfl_xor(s, o);
        if (lane == 0) mu_s[0] = s * (1.f/(196.f*128.f));
    } else if (wv == 1) {
        float s = rs2[lane] + rs2[lane + 64];
#pragma unroll
        for (int o = 1; o < 64; o <<= 1) s += __shfl_xor(s, o);
        if (lane == 0) mu_s[1] = s * (1.f/(196.f*128.f));
    }

    floatx4 acc[4][4];
#pragma unroll
    for (int i = 0; i < 4; i++)
#pragma unroll
        for (int j = 0; j < 4; j++)
#pragma unroll
            for (int r = 0; r < 4; r++) acc[i][j][r] = 0.f;

    const int np  = t & 15;               // token pair 0..15
    const int dch = t >> 4;               // d-chunk of 8, 0..15

    ushort8 cva, cvb, cwa, cwb;           // current tile regs
    {                                     // prologue: tile n0=0 (all n<196)
        const int na = 2*np, nb = na + 1;
        cva = *(const ushort8*)(X1 + (na << 7) + dch*8);
        cwa = *(const ushort8*)(X2 + (na << 7) + dch*8);
        cvb = *(const ushort8*)(X1 + (nb << 7) + dch*8);
        cwb = *(const ushort8*)(X2 + (nb << 7) + dch*8);
    }

    for (int n0 = 0; n0 < 224; n0 += 32) {
        __syncthreads();                  // prev iteration's LDS reads done
#pragma unroll
        for (int e = 0; e < 8; e++) {     // pack/write current tile
            x1s[(dch*8 + e)*18 + np] = (u32)cva[e] | ((u32)cvb[e] << 16);
            x2s[(dch*8 + e)*18 + np] = (u32)cwa[e] | ((u32)cwb[e] << 16);
        }
        __syncthreads();                  // writes visible
        if (n0 + 32 < 224) {              // T14: issue next tile's loads NOW
            const int na = n0 + 32 + 2*np, nb = na + 1;
            ushort8 z;
#pragma unroll
            for (int e = 0; e < 8; e++) z[e] = 0;
            ushort8 nva = z, nvb = z, nwa = z, nwb = z;
            if (na < 196) {
                nva = *(const ushort8*)(X1 + (na << 7) + dch*8);
                nwa = *(const ushort8*)(X2 + (na << 7) + dch*8);
            }
            if (nb < 196) {
                nvb = *(const ushort8*)(X1 + (nb << 7) + dch*8);
                nwb = *(const ushort8*)(X2 + (nb << 7) + dch*8);
            }
            cva = nva; cvb = nvb; cwa = nwa; cwb = nwb;
        }
        bf16x8 af[4], bfr[4];             // MFMA cluster hides the loads
#pragma unroll
        for (int i = 0; i < 4; i++) {
            const int base = (wr*64 + i*16 + c)*18 + q*4;
            u32 tmp[4];
            *(u32x2*)&tmp[0] = *(const u32x2*)&x1s[base];
            *(u32x2*)&tmp[2] = *(const u32x2*)&x1s[base + 2];
            __builtin_memcpy(&af[i], tmp, 16);
        }
#pragma unroll
        for (int j = 0; j < 4; j++) {
            const int base = (wc*64 + j*16 + c)*18 + q*4;
            u32 tmp[4];
            *(u32x2*)&tmp[0] = *(const u32x2*)&x2s[base];
            *(u32x2*)&tmp[2] = *(const u32x2*)&x2s[base + 2];
            __builtin_memcpy(&bfr[j], tmp, 16);
        }
#pragma unroll
        for (int i = 0; i < 4; i++)
#pragma unroll
            for (int j = 0; j < 4; j++)
                acc[i][j] = __builtin_amdgcn_mfma_f32_16x16x32_bf16(af[i], bfr[j], acc[i][j], 0, 0, 0);
    }

    const float mu1 = mu_s[0], mu2 = mu_s[1];
    const float invL = 1.f/196.f;
    float csq[4] = {0.f, 0.f, 0.f, 0.f};
#pragma unroll
    for (int i = 0; i < 4; i++)
#pragma unroll
        for (int j = 0; j < 4; j++)
#pragma unroll
            for (int r = 0; r < 4; r++) {
                const int d = wr*64 + i*16 + q*4 + r;
                const int e = wc*64 + j*16 + c;
                const float v = acc[i][j][r]*invL - mu2*rs1[d]*invL - mu1*rs2[e]*invL + mu1*mu2;
                acc[i][j][r] = v;
                csq[j] += v*v;
            }
#pragma unroll
    for (int j = 0; j < 4; j++) {
        float s = csq[j];
        s += __shfl_xor(s, 16);
        s += __shfl_xor(s, 32);
        csq[j] = s;
    }
    if (q == 0) {
#pragma unroll
        for (int j = 0; j < 4; j++) colsq[wr][wc*64 + j*16 + c] = csq[j];
    }
    __syncthreads();
    if (t < 128) {
        const float nr = sqrtf(colsq[0][t] + colsq[1][t]);
        nrm_inv[t] = 1.f / fmaxf(nr, 1e-12f);
    }
    __syncthreads();
    float* dst = cov + ((long)b*3 + p)*16384;
#pragma unroll
    for (int i = 0; i < 4; i++)
#pragma unroll
        for (int j = 0; j < 4; j++) {
            const int e = wc*64 + j*16 + c;
            const float ni = nrm_inv[e];
#pragma unroll
            for (int r = 0; r < 4; r++) {
                const int d = wr*64 + i*16 + q*4 + r;
                dst[(d << 7) + e] = acc[i][j][r] * ni;
            }
        }
}

// ---------------------------------------------------------------------------
// K3: fused conv1+GELU+conv2; 2 blocks per batch (conv2 y-halves) -> 512
// blocks = 2 blocks/CU. Z slice (<=33 rows, 1-row overlap) kept in LDS.
// ---------------------------------------------------------------------------
__global__ __launch_bounds__(256)
void k_convs(const float* __restrict__ cov, const float* __restrict__ w1,
             const float* __restrict__ w2, bf16_t* __restrict__ Xb)
{
    __shared__ float Z[3*33*63];          // 24.9 KB
    __shared__ float W1s[81];
    __shared__ float W2s[81];
    const int t = threadIdx.x;
    const int b = blockIdx.x >> 1, half = blockIdx.x & 1;
    const int zy0 = half ? 32 : 0;        // first global Z row this block needs
    const int nzy = half ? 31 : 33;       // Z rows computed
    const int y20 = half ? 16 : 0;        // first conv2 output row
    const int ny2 = half ? 15 : 16;       // conv2 output rows
    if (t < 81) { W1s[t] = w1[t]; W2s[t] = w2[t]; }
    __syncthreads();
    const float* C = cov + (long)b*3*16384;
    const int ztot = 3*nzy*63;
    for (int idx = t; idx < ztot; idx += 256) {
        const int o = idx / (nzy*63), rem = idx - o*(nzy*63);
        const int yl = rem / 63, xx = rem - yl*63;
        const int y = zy0 + yl;
        float a = 0.f;
#pragma unroll
        for (int i = 0; i < 3; i++) {
            const float* Ci = C + i*16384 + (2*y)*128 + 2*xx;
            const float* Wi = &W1s[o*27 + i*9];
            a += Ci[0]*Wi[0]   + Ci[1]*Wi[1]   + Ci[2]*Wi[2]
               + Ci[128]*Wi[3] + Ci[129]*Wi[4] + Ci[130]*Wi[5]
               + Ci[256]*Wi[6] + Ci[257]*Wi[7] + Ci[258]*Wi[8];
        }
        Z[o*2079 + yl*63 + xx] = 0.5f*a*(1.0f + erff(a*0.70710678118654752f));
    }
    __syncthreads();
    const int c2tot = 3*ny2*31;
    for (int idx = t; idx < c2tot; idx += 256) {
        const int o = idx / (ny2*31), rem = idx - o*(ny2*31);
        const int y2l = rem / 31, x2 = rem - y2l*31;
        float a = 0.f;
#pragma unroll
        for (int i = 0; i < 3; i++) {
            const float* Zi = Z + i*2079 + (2*y2l)*63 + 2*x2;
            const float* Wi = &W2s[(o*3+i)*9];
            a += Zi[0]*Wi[0]   + Zi[1]*Wi[1]   + Zi[2]*Wi[2]
               + Zi[63]*Wi[3]  + Zi[64]*Wi[4]  + Zi[65]*Wi[5]
               + Zi[126]*Wi[6] + Zi[127]*Wi[7] + Zi[128]*Wi[8];
        }
        const int oy2 = y20 + y2l;
        Xb[(long)b*3712 + 768 + o*961 + oy2*31 + x2] = (bf16_t)a;
    }
}

// ---------------------------------------------------------------------------
// K4c: MFMA GEMM partial[s][m][n] = Xb[m][ks..] @ Wb[n][ks..]^T
// grid (nt=8, mt=2, split=4); 128x128 tile, K-split 928 (29 k-tiles) each.
// Triple-buffered counted-vmcnt pipeline (r8).
// ---------------------------------------------------------------------------
__global__ __launch_bounds__(256, 2)
void k_gemm_cls(const bf16_t* __restrict__ Xb, const bf16_t* __restrict__ Wb,
                float* __restrict__ partial)
{
    __shared__ bf16_t As[3][128*32];
    __shared__ bf16_t Bs[3][128*32];

    const int t = threadIdx.x;
    const int lane = t & 63;
    const int wv = t >> 6;
    const int wr = wv >> 1, wc = wv & 1;
    const int q = lane >> 4;
    const int c = lane & 15;
    const int nt = blockIdx.x;
    const int mt = blockIdx.y;
    const int sp = blockIdx.z;

    const int srow  = t >> 2;
    const int skoff = (t & 3) * 8;
    const int m0 = mt * 128, n0 = nt * 128;
    const int kbase = sp * 928;
    const bf16_t* ag0 = Xb + (m0 + srow) * 3712 + kbase + skoff;
    const bf16_t* ag1 = Xb + (m0 + srow + 64) * 3712 + kbase + skoff;
    const bf16_t* bg0 = Wb + (n0 + srow) * 3712 + kbase + skoff;
    const bf16_t* bg1 = Wb + (n0 + srow + 64) * 3712 + kbase + skoff;

#define GSTAGE(B, kk)                                                    \
    {                                                                    \
        const int kn_ = (kk) * 32;                                       \
        async_copy16(ag0 + kn_, &As[B][t*8]);                            \
        async_copy16(ag1 + kn_, &As[B][2048 + t*8]);                     \
        async_copy16(bg0 + kn_, &Bs[B][t*8]);                            \
        async_copy16(bg1 + kn_, &Bs[B][2048 + t*8]);                     \
    }

#define GCOMPUTE(B)                                                      \
    {                                                                    \
        bf16x8 af[4], bfr[4];                                            \
        _Pragma("unroll")                                                \
        for (int i = 0; i < 4; i++)                                      \
            af[i] = *(const bf16x8*)&As[B][(wr*64 + i*16 + c)*32 + q*8]; \
        _Pragma("unroll")                                                \
        for (int j = 0; j < 4; j++)                                      \
            bfr[j] = *(const bf16x8*)&Bs[B][(wc*64 + j*16 + c)*32 + q*8];\
        _Pragma("unroll")                                                \
        for (int i = 0; i < 4; i++)                                      \
            _Pragma("unroll")                                            \
            for (int j = 0; j < 4; j++)                                  \
                acc[i][j] = __builtin_amdgcn_mfma_f32_16x16x32_bf16(af[i], bfr[j], acc[i][j], 0, 0, 0); \
    }

    floatx4 acc[4][4];
#pragma unroll
    for (int i = 0; i < 4; i++)
#pragma unroll
        for (int j = 0; j < 4; j++)
#pragma unroll
            for (int r = 0; r < 4; r++) acc[i][j][r] = 0.f;

    GSTAGE(0, 0);
    GSTAGE(1, 1);
    GSTAGE(2, 2);

    for (int ks = 0; ks < 27; ks++) {     // 29 tiles: loop does 0..26
        const int buf = ks % 3;
        asm volatile("s_waitcnt vmcnt(8)" ::: "memory");
        __builtin_amdgcn_s_barrier();
        GCOMPUTE(buf);
        __builtin_amdgcn_s_barrier();
        if (ks < 26) GSTAGE(buf, ks + 3);
    }
    asm volatile("s_waitcnt vmcnt(4)" ::: "memory");
    __builtin_amdgcn_s_barrier();
    GCOMPUTE(0);
    __builtin_amdgcn_s_barrier();
    asm volatile("s_waitcnt vmcnt(0)" ::: "memory");
    __builtin_amdgcn_s_barrier();
    GCOMPUTE(1);

#undef GSTAGE
#undef GCOMPUTE

    float* base = partial + ((long)sp*256 + m0)*1024 + n0;
#pragma unroll
    for (int i = 0; i < 4; i++)
#pragma unroll
        for (int r = 0; r < 4; r++) {
            const int row = wr*64 + i*16 + q*4 + r;
#pragma unroll
            for (int j = 0; j < 4; j++)
                base[row*1024 + wc*64 + j*16 + c] = acc[i][j][r];
        }
}

// ---------------------------------------------------------------------------
// K4d: out[m][n] = 0.5*(sum_s partial[s][m][n] + b1[n] + b2[n]), n<1000
// ---------------------------------------------------------------------------
__global__ __launch_bounds__(256)
void k_cls_fin(const float* __restrict__ partial, const float* __restrict__ b1,
               const float* __restrict__ b2, float* __restrict__ out)
{
    const int idx = blockIdx.x * 256 + threadIdx.x;   // 256,000
    const int m = idx / 1000, n = idx - m*1000;
    float s = partial[(m)*1024 + n] + partial[(256 + m)*1024 + n]
            + partial[(512 + m)*1024 + n] + partial[(768 + m)*1024 + n];
    out[idx] = 0.5f*(s + b1[n] + b2[n]);
}

// ---------------------------------------------------------------------------
extern "C" void kernel_launch(void* const* d_in, const int* in_sizes, int n_in,
                              void* d_out, int out_size, void* d_ws, size_t ws_size,
                              hipStream_t stream) {
    const float* cls = (const float*)d_in[0];
    const float* x   = (const float*)d_in[1];
    const float* pw  = (const float*)d_in[2];
    const float* pb  = (const float*)d_in[3];
    const float* lng = (const float*)d_in[4];
    const float* lnb = (const float*)d_in[5];
    const float* c1w = (const float*)d_in[6];
    const float* c2w = (const float*)d_in[7];
    const float* w1  = (const float*)d_in[8];
    const float* b1  = (const float*)d_in[9];
    const float* w2  = (const float*)d_in[10];
    const float* b2  = (const float*)d_in[11];

    char* ws = (char*)d_ws;
    // lifetimes:
    //   hn      [0, 51,380,224)                 proj_ln out -> cov in
    //   xbf     [51,380,224, +77,070,336)       dead after proj_ln
    //   covb    [51,380,224, +50,331,648)       reuses xbf; cov out -> convs in
    //   wt      [128,450,560, +786,432)         dead after proj_ln
    //   csum    [129,236,992, +524,288)
    //   Xb      [129,761,280, +1,900,544)
    //   Wb      [131,661,824, +7,602,176)
    //   part    [139,264,000, +4,194,304)
    bf16_t* hn    = (bf16_t*)(ws);
    bf16_t* xbf   = (bf16_t*)(ws + 51380224ull);
    float*  covb  = (float*) (ws + 51380224ull);
    bf16_t* wt    = (bf16_t*)(ws + 128450560ull);
    float*  csum  = (float*) (ws + 129236992ull);
    bf16_t* Xb    = (bf16_t*)(ws + 129761280ull);
    bf16_t* Wb    = (bf16_t*)(ws + 131661824ull);
    float*  part  = (float*) (ws + 139264000ull);
    float*  out   = (float*)d_out;

    k_prep<<<23168, 256, 0, stream>>>(x, xbf, pw, wt, cls, Xb, csum, w1, w2, Wb);
    k_proj_ln<<<1568, 256, 0, stream>>>(xbf, wt, pb, lng, lnb, hn, csum);
    k_cov<<<dim3(256, 3), 256, 0, stream>>>(hn, csum, covb);
    k_convs<<<512, 256, 0, stream>>>(covb, c1w, c2w, Xb);
    k_gemm_cls<<<dim3(8, 2, 4), 256, 0, stream>>>(Xb, Wb, part);
    k_cls_fin<<<1000, 256, 0, stream>>>(part, b1, b2, out);
}